// Round 3
// baseline (330.707 us; speedup 1.0000x reference)
//
#include <hip/hip_runtime.h>

#define BOHR_F 0.5291772105638411f
#define HA_D   27.211386024367243
#define A1_F   0.4289f
#define A2_F   4.4407f
#define S6_F   1.0f
#define S8_F   0.7875f
#define KCN_F  16.0f
#define WF_F   4.0f
#define EPS_F  1.1920929e-07f

__device__ __forceinline__ float smooth_cutoff(float dr, float r_on, float r_cut) {
    float r_c = r_cut * r_cut;
    float r_o = r_on * r_on;
    float r   = dr * dr;
    float den = (r_c - r_o);
    float t   = r_c - r;
    float inner = (dr < r_cut)
        ? (t * t * (r_c + 2.0f * r - 3.0f * r_o)) / (den * den * den)
        : 0.0f;
    return (dr < r_on) ? 1.0f : inner;
}

__device__ __forceinline__ int get_xcc() {
    int x;
    asm("s_getreg_b32 %0, hwreg(HW_REG_XCC_ID)" : "=s"(x));
    return x & 7;
}

// Pass 1: per-edge CN contribution, one edge per thread.
// REP=true: scatter into this physical XCD's replica with a workgroup-scope
// atomic (L2-local: all writers of replica r are on XCD r; the end-of-kernel
// release writes L2 back so pass 2 sees the sums).
// REP=false: single copy, device-scope atomicAdd.
template<bool REP>
__global__ __launch_bounds__(256)
void k_edges_cn(const float* __restrict__ dr_vec,
                const int*  __restrict__ idx_i,
                const int*  __restrict__ idx_j,
                const int*  __restrict__ numbers,
                const float* __restrict__ rcov,
                float* __restrict__ cn_rep,   // [n_rep, n_atoms]
                int n_edges, int n_atoms) {
    int e = blockIdx.x * blockDim.x + threadIdx.x;
    if (e >= n_edges) return;
    float x = dr_vec[3 * e + 0];
    float y = dr_vec[3 * e + 1];
    float z = dr_vec[3 * e + 2];
    float dr = sqrtf(x * x + y * y + z * z) / BOHR_F;
    int i = idx_i[e];
    int j = idx_j[e];
    int Zi = numbers[i];
    int Zj = numbers[j];
    float rc = rcov[Zi] + rcov[Zj];
    if (dr > 0.0f) {
        float count = 1.0f / (1.0f + expf(-KCN_F * (rc / dr - 1.0f)));
        float m = smooth_cutoff(dr, 20.0f, 25.0f) * count;
        if (REP) {
            float* my_cn = cn_rep + (size_t)get_xcc() * n_atoms;
            __hip_atomic_fetch_add(&my_cn[i], m, __ATOMIC_RELAXED,
                                   __HIP_MEMORY_SCOPE_WORKGROUP);
        } else {
            atomicAdd(&cn_rep[i], m);
        }
    }
}

// Pass 2: sum replicas, then per-atom normalized gaussian weights [N,5].
__global__ __launch_bounds__(256)
void k_atom_weights(const float* __restrict__ cn_rep, // [n_rep,N]
                    const int*  __restrict__ numbers,
                    const float* __restrict__ ref_cn_table, // [95,5]
                    float* __restrict__ weights,            // [N,5]
                    int n_atoms, int n_rep) {
    int tid = blockIdx.x * blockDim.x + threadIdx.x;
    int stride = gridDim.x * blockDim.x;
    for (int a = tid; a < n_atoms; a += stride) {
        float c = 0.0f;
        for (int r = 0; r < n_rep; ++r)
            c += cn_rep[(size_t)r * n_atoms + a];
        int Z = numbers[a];
        float w[5];
        float s = 0.0f;
#pragma unroll
        for (int r = 0; r < 5; ++r) {
            float rcn = ref_cn_table[Z * 5 + r];
            float d = rcn - c;
            float wv = (rcn >= 0.0f) ? expf(-WF_F * d * d) : 0.0f;
            w[r] = wv;
            s += wv;
        }
        float den = s + EPS_F;
#pragma unroll
        for (int r = 0; r < 5; ++r) {
            weights[a * 5 + r] = w[r] / den;
        }
    }
}

// Pass 3: per-edge C6 + BJ-damped energy, one edge per thread,
// reduced (double) into e_acc.
__global__ __launch_bounds__(256)
void k_edges_energy(const float* __restrict__ dr_vec,
                    const int*  __restrict__ idx_i,
                    const int*  __restrict__ idx_j,
                    const int*  __restrict__ numbers,
                    const float* __restrict__ r4r2,
                    const float* __restrict__ ref_c6,   // [95,95,5,5]
                    const float* __restrict__ weights,  // [N,5]
                    double* __restrict__ e_acc,
                    int n_edges) {
    double local = 0.0;
    int e = blockIdx.x * blockDim.x + threadIdx.x;
    if (e < n_edges) {
        float x = dr_vec[3 * e + 0];
        float y = dr_vec[3 * e + 1];
        float z = dr_vec[3 * e + 2];
        float dr = sqrtf(x * x + y * y + z * z) / BOHR_F;
        int i = idx_i[e];
        int j = idx_j[e];
        int Zi = numbers[i];
        int Zj = numbers[j];
        float qq = 3.0f * r4r2[Zi] * r4r2[Zj];

        float wi[5], wj[5];
#pragma unroll
        for (int r = 0; r < 5; ++r) {
            wi[r] = weights[i * 5 + r];
            wj[r] = weights[j * 5 + r];
        }
        const float* c6t = ref_c6 + ((size_t)Zj * 95 + (size_t)Zi) * 25;
        float c6 = 0.0f;
#pragma unroll
        for (int a = 0; a < 5; ++a) {
#pragma unroll
            for (int b = 0; b < 5; ++b) {
                c6 += wj[a] * wi[b] * c6t[a * 5 + b];
            }
        }

        float rr = A1_F * sqrtf(qq) + A2_F;
        float dr2 = dr * dr;
        float dr6 = dr2 * dr2 * dr2;
        float dr8 = dr6 * dr2;
        float rr2 = rr * rr;
        float rr6 = rr2 * rr2 * rr2;
        float rr8 = rr6 * rr2;
        float damped = -c6 * (S6_F / (dr6 + rr6) + S8_F * qq / (dr8 + rr8));
        float energy = smooth_cutoff(dr, 55.0f, 60.0f) * damped * 0.5f;
        local = (double)energy;
    }

    // block reduction (wave64 shuffle, then LDS across waves)
    __shared__ double sdata[4];
    for (int off = 32; off > 0; off >>= 1)
        local += __shfl_down(local, off, 64);
    int lane = threadIdx.x & 63;
    int wid  = threadIdx.x >> 6;
    if (lane == 0) sdata[wid] = local;
    __syncthreads();
    if (threadIdx.x == 0) {
        double s = sdata[0] + sdata[1] + sdata[2] + sdata[3];
        atomicAdd(e_acc, s);
    }
}

__global__ void k_finalize(const double* __restrict__ e_acc,
                           float* __restrict__ out) {
    out[0] = (float)(e_acc[0] * HA_D);
}

extern "C" void kernel_launch(void* const* d_in, const int* in_sizes, int n_in,
                              void* d_out, int out_size, void* d_ws, size_t ws_size,
                              hipStream_t stream) {
    const float* dr_vec      = (const float*)d_in[0];
    const float* ref_cn_tab  = (const float*)d_in[1];
    const float* ref_c6_tab  = (const float*)d_in[2];
    const float* r4r2        = (const float*)d_in[3];
    const float* rcov        = (const float*)d_in[4];
    const int*   numbers     = (const int*)d_in[5];
    const int*   idx         = (const int*)d_in[6];

    int n_atoms = in_sizes[5];
    int n_edges = in_sizes[6] / 2;
    const int* idx_i = idx;
    const int* idx_j = idx + n_edges;

    // workspace layout: [e_acc 16B][cn_rep: n_rep*N f32][weights: N*5 f32]
    char* ws = (char*)d_ws;
    double* e_acc = (double*)ws;

    int n_rep = 8;
    size_t cn_off = 16;
    size_t need = cn_off + (size_t)n_rep * n_atoms * 4 + (size_t)n_atoms * 5 * 4;
    if (ws_size < need) n_rep = 1;

    size_t w_off = cn_off + (size_t)n_rep * n_atoms * 4;
    float* cn_rep  = (float*)(ws + cn_off);
    float* weights = (float*)(ws + w_off);

    // zero accumulator + cn replicas (weights fully overwritten before read)
    hipMemsetAsync(d_ws, 0, w_off, stream);

    const int block = 256;
    int grid_e = (n_edges + block - 1) / block;   // one edge per thread
    int grid_a = (n_atoms + block - 1) / block;
    if (grid_a > 2048) grid_a = 2048;

    if (n_rep == 8)
        k_edges_cn<true><<<grid_e, block, 0, stream>>>(
            dr_vec, idx_i, idx_j, numbers, rcov, cn_rep, n_edges, n_atoms);
    else
        k_edges_cn<false><<<grid_e, block, 0, stream>>>(
            dr_vec, idx_i, idx_j, numbers, rcov, cn_rep, n_edges, n_atoms);

    k_atom_weights<<<grid_a, block, 0, stream>>>(
        cn_rep, numbers, ref_cn_tab, weights, n_atoms, n_rep);

    k_edges_energy<<<grid_e, block, 0, stream>>>(
        dr_vec, idx_i, idx_j, numbers, r4r2, ref_c6_tab, weights,
        e_acc, n_edges);

    k_finalize<<<1, 1, 0, stream>>>(e_acc, (float*)d_out);
}

// Round 4
// 240.409 us; speedup vs baseline: 1.3756x; 1.3756x over previous
//
#include <hip/hip_runtime.h>

#define BOHR_F 0.5291772105638411f
#define HA_D   27.211386024367243
#define A1_F   0.4289f
#define A2_F   4.4407f
#define S6_F   1.0f
#define S8_F   0.7875f
#define KCN_F  16.0f
#define WF_F   4.0f
#define EPS_F  1.1920929e-07f

#define CN_SCALE   8388608.0f          // 2^23
#define CN_INV     (1.0f/8388608.0f)

__device__ __forceinline__ float smooth_cutoff(float dr, float r_on, float r_cut) {
    float r_c = r_cut * r_cut;
    float r_o = r_on * r_on;
    float r   = dr * dr;
    float den = (r_c - r_o);
    float t   = r_c - r;
    float inner = (dr < r_cut)
        ? (t * t * (r_c + 2.0f * r - 3.0f * r_o)) / (den * den * den)
        : 0.0f;
    return (dr < r_on) ? 1.0f : inner;
}

// Pass 1: per-edge CN contribution -> u32 fixed-point atomic; stash dr.
template<bool STASH>
__global__ __launch_bounds__(256)
void k_edges_cn(const float* __restrict__ dr_vec,
                const int*  __restrict__ idx_i,
                const int*  __restrict__ idx_j,
                const int*  __restrict__ numbers,
                const float* __restrict__ rcov,
                unsigned int* __restrict__ cn_u32,
                float* __restrict__ dr_stash,
                int n_edges) {
    int e = blockIdx.x * blockDim.x + threadIdx.x;
    if (e >= n_edges) return;
    float x = dr_vec[3 * e + 0];
    float y = dr_vec[3 * e + 1];
    float z = dr_vec[3 * e + 2];
    float dr = sqrtf(x * x + y * y + z * z) / BOHR_F;
    if (STASH) dr_stash[e] = dr;
    int i = idx_i[e];
    int j = idx_j[e];
    int Zi = numbers[i];
    int Zj = numbers[j];
    float rc = rcov[Zi] + rcov[Zj];
    if (dr > 0.0f) {
        float count = 1.0f / (1.0f + expf(-KCN_F * (rc / dr - 1.0f)));
        float m = smooth_cutoff(dr, 20.0f, 25.0f) * count;
        unsigned int q = (unsigned int)(m * CN_SCALE + 0.5f);
        if (q) atomicAdd(&cn_u32[i], q);
    }
}

// Pass 2: decode cn, per-atom normalized gaussian weights [N,5].
__global__ __launch_bounds__(256)
void k_atom_weights(const unsigned int* __restrict__ cn_u32,
                    const int*  __restrict__ numbers,
                    const float* __restrict__ ref_cn_table, // [95,5]
                    float* __restrict__ weights,            // [N,5]
                    int n_atoms) {
    int tid = blockIdx.x * blockDim.x + threadIdx.x;
    int stride = gridDim.x * blockDim.x;
    for (int a = tid; a < n_atoms; a += stride) {
        float c = (float)cn_u32[a] * CN_INV;
        int Z = numbers[a];
        float w[5];
        float s = 0.0f;
#pragma unroll
        for (int r = 0; r < 5; ++r) {
            float rcn = ref_cn_table[Z * 5 + r];
            float d = rcn - c;
            float wv = (rcn >= 0.0f) ? expf(-WF_F * d * d) : 0.0f;
            w[r] = wv;
            s += wv;
        }
        float den = s + EPS_F;
#pragma unroll
        for (int r = 0; r < 5; ++r) {
            weights[a * 5 + r] = w[r] / den;
        }
    }
}

// Pass 3: 4 edges per thread (independent gather chains for MLP),
// C6 + BJ-damped energy, double reduction into e_acc.
template<bool STASH>
__global__ __launch_bounds__(256)
void k_edges_energy(const float* __restrict__ dr_vec,
                    const float* __restrict__ dr_stash,
                    const int*  __restrict__ idx_i,
                    const int*  __restrict__ idx_j,
                    const int*  __restrict__ numbers,
                    const float* __restrict__ r4r2,
                    const float* __restrict__ ref_c6,   // [95,95,5,5]
                    const float* __restrict__ weights,  // [N,5]
                    double* __restrict__ e_acc,
                    int n_edges) {
    double local = 0.0;
    int nquad = (n_edges + 3) >> 2;
    int tid = blockIdx.x * blockDim.x + threadIdx.x;
    int stride = gridDim.x * blockDim.x;
    for (int qd = tid; qd < nquad; qd += stride) {
        int e0 = qd << 2;
        int ne = n_edges - e0;
        if (ne > 4) ne = 4;
        if (ne == 4) {
            // batched coalesced loads
            int4 i4 = *reinterpret_cast<const int4*>(idx_i + e0);
            int4 j4 = *reinterpret_cast<const int4*>(idx_j + e0);
            int ia[4] = { i4.x, i4.y, i4.z, i4.w };
            int ja[4] = { j4.x, j4.y, j4.z, j4.w };
            float drq[4];
            if (STASH) {
                float4 d4 = *reinterpret_cast<const float4*>(dr_stash + e0);
                drq[0] = d4.x; drq[1] = d4.y; drq[2] = d4.z; drq[3] = d4.w;
            } else {
                float4 v0 = *reinterpret_cast<const float4*>(dr_vec + 3 * e0);
                float4 v1 = *reinterpret_cast<const float4*>(dr_vec + 3 * e0 + 4);
                float4 v2 = *reinterpret_cast<const float4*>(dr_vec + 3 * e0 + 8);
                drq[0] = sqrtf(v0.x*v0.x + v0.y*v0.y + v0.z*v0.z) / BOHR_F;
                drq[1] = sqrtf(v0.w*v0.w + v1.x*v1.x + v1.y*v1.y) / BOHR_F;
                drq[2] = sqrtf(v1.z*v1.z + v1.w*v1.w + v2.x*v2.x) / BOHR_F;
                drq[3] = sqrtf(v2.y*v2.y + v2.z*v2.z + v2.w*v2.w) / BOHR_F;
            }
            int Zi[4], Zj[4];
#pragma unroll
            for (int k = 0; k < 4; ++k) { Zi[k] = numbers[ia[k]]; Zj[k] = numbers[ja[k]]; }
            float wi[4][5], wj[4][5];
#pragma unroll
            for (int k = 0; k < 4; ++k) {
#pragma unroll
                for (int r = 0; r < 5; ++r) {
                    wi[k][r] = weights[ia[k] * 5 + r];
                    wj[k][r] = weights[ja[k] * 5 + r];
                }
            }
#pragma unroll
            for (int k = 0; k < 4; ++k) {
                float qq = 3.0f * r4r2[Zi[k]] * r4r2[Zj[k]];
                const float* c6t = ref_c6 + ((size_t)Zj[k] * 95 + (size_t)Zi[k]) * 25;
                float c6 = 0.0f;
#pragma unroll
                for (int a = 0; a < 5; ++a) {
#pragma unroll
                    for (int b = 0; b < 5; ++b) {
                        c6 += wj[k][a] * wi[k][b] * c6t[a * 5 + b];
                    }
                }
                float dr = drq[k];
                float rr = A1_F * sqrtf(qq) + A2_F;
                float dr2 = dr * dr;
                float dr6 = dr2 * dr2 * dr2;
                float dr8 = dr6 * dr2;
                float rr2 = rr * rr;
                float rr6 = rr2 * rr2 * rr2;
                float rr8 = rr6 * rr2;
                float damped = -c6 * (S6_F / (dr6 + rr6) + S8_F * qq / (dr8 + rr8));
                local += (double)(smooth_cutoff(dr, 55.0f, 60.0f) * damped * 0.5f);
            }
        } else {
            for (int k = 0; k < ne; ++k) {
                int e = e0 + k;
                float dr;
                if (STASH) dr = dr_stash[e];
                else {
                    float x = dr_vec[3*e], y = dr_vec[3*e+1], z = dr_vec[3*e+2];
                    dr = sqrtf(x*x + y*y + z*z) / BOHR_F;
                }
                int i = idx_i[e], j = idx_j[e];
                int zi = numbers[i], zj = numbers[j];
                float qq = 3.0f * r4r2[zi] * r4r2[zj];
                const float* c6t = ref_c6 + ((size_t)zj * 95 + (size_t)zi) * 25;
                float c6 = 0.0f;
                for (int a = 0; a < 5; ++a)
                    for (int b = 0; b < 5; ++b)
                        c6 += weights[j*5+a] * weights[i*5+b] * c6t[a*5+b];
                float rr = A1_F * sqrtf(qq) + A2_F;
                float dr2 = dr * dr;
                float dr6 = dr2 * dr2 * dr2;
                float dr8 = dr6 * dr2;
                float rr2 = rr * rr;
                float rr6 = rr2 * rr2 * rr2;
                float rr8 = rr6 * rr2;
                float damped = -c6 * (S6_F / (dr6 + rr6) + S8_F * qq / (dr8 + rr8));
                local += (double)(smooth_cutoff(dr, 55.0f, 60.0f) * damped * 0.5f);
            }
        }
    }

    // block reduction (wave64 shuffle, then LDS across waves)
    __shared__ double sdata[4];
    for (int off = 32; off > 0; off >>= 1)
        local += __shfl_down(local, off, 64);
    int lane = threadIdx.x & 63;
    int wid  = threadIdx.x >> 6;
    if (lane == 0) sdata[wid] = local;
    __syncthreads();
    if (threadIdx.x == 0) {
        double s = sdata[0] + sdata[1] + sdata[2] + sdata[3];
        atomicAdd(e_acc, s);
    }
}

__global__ void k_finalize(const double* __restrict__ e_acc,
                           float* __restrict__ out) {
    out[0] = (float)(e_acc[0] * HA_D);
}

extern "C" void kernel_launch(void* const* d_in, const int* in_sizes, int n_in,
                              void* d_out, int out_size, void* d_ws, size_t ws_size,
                              hipStream_t stream) {
    const float* dr_vec      = (const float*)d_in[0];
    const float* ref_cn_tab  = (const float*)d_in[1];
    const float* ref_c6_tab  = (const float*)d_in[2];
    const float* r4r2        = (const float*)d_in[3];
    const float* rcov        = (const float*)d_in[4];
    const int*   numbers     = (const int*)d_in[5];
    const int*   idx         = (const int*)d_in[6];

    int n_atoms = in_sizes[5];
    int n_edges = in_sizes[6] / 2;
    const int* idx_i = idx;
    const int* idx_j = idx + n_edges;

    // ws layout: [e_acc 16B][cn_u32: N][weights: N*5 f32][dr: E f32]
    char* ws = (char*)d_ws;
    double* e_acc = (double*)ws;
    size_t cn_off = 16;
    size_t w_off  = cn_off + (size_t)n_atoms * 4;
    size_t dr_off = w_off + (size_t)n_atoms * 5 * 4;
    bool stash = (ws_size >= dr_off + (size_t)n_edges * 4);

    unsigned int* cn_u32 = (unsigned int*)(ws + cn_off);
    float* weights  = (float*)(ws + w_off);
    float* dr_stash = stash ? (float*)(ws + dr_off) : nullptr;

    // zero accumulator + cn (weights/dr fully overwritten before read)
    hipMemsetAsync(d_ws, 0, w_off, stream);

    const int block = 256;
    int grid_e = (n_edges + block - 1) / block;   // cn: one edge per thread
    int grid_a = (n_atoms + block - 1) / block;
    if (grid_a > 2048) grid_a = 2048;
    int nquad = (n_edges + 3) >> 2;
    int grid_q = (nquad + block - 1) / block;     // energy: 4 edges per thread
    if (grid_q > 8192) grid_q = 8192;

    if (stash)
        k_edges_cn<true><<<grid_e, block, 0, stream>>>(
            dr_vec, idx_i, idx_j, numbers, rcov, cn_u32, dr_stash, n_edges);
    else
        k_edges_cn<false><<<grid_e, block, 0, stream>>>(
            dr_vec, idx_i, idx_j, numbers, rcov, cn_u32, nullptr, n_edges);

    k_atom_weights<<<grid_a, block, 0, stream>>>(
        cn_u32, numbers, ref_cn_tab, weights, n_atoms);

    if (stash)
        k_edges_energy<true><<<grid_q, block, 0, stream>>>(
            dr_vec, dr_stash, idx_i, idx_j, numbers, r4r2, ref_c6_tab, weights,
            e_acc, n_edges);
    else
        k_edges_energy<false><<<grid_q, block, 0, stream>>>(
            dr_vec, nullptr, idx_i, idx_j, numbers, r4r2, ref_c6_tab, weights,
            e_acc, n_edges);

    k_finalize<<<1, 1, 0, stream>>>(e_acc, (float*)d_out);
}